// Round 9
// baseline (673.183 us; speedup 1.0000x reference)
//
#include <hip/hip_runtime.h>

#define NN 50000
#define NE 400000
#define NG 512

typedef __bf16 bf16x8 __attribute__((ext_vector_type(8)));
typedef float f32x4 __attribute__((ext_vector_type(4)));
typedef unsigned short us8 __attribute__((ext_vector_type(8)));
typedef _Float16 half8 __attribute__((ext_vector_type(8)));

__device__ __forceinline__ float frcp(float x) { return __builtin_amdgcn_rcpf(x); }
__device__ __forceinline__ float silu_f(float x) { return x * frcp(1.f + __expf(-x)); }
__device__ __forceinline__ float tanh_f(float x) { return 1.f - 2.f * frcp(__expf(2.f * x) + 1.f); }
__device__ __forceinline__ __bf16 f2bf(float f) {
    unsigned u = __builtin_bit_cast(unsigned, f);
    u += 0x7fffu + ((u >> 16) & 1u);
    unsigned short s = (unsigned short)(u >> 16);
    return __builtin_bit_cast(__bf16, s);
}
__device__ __forceinline__ unsigned short f2bfu(float f) {
    return __builtin_bit_cast(unsigned short, f2bf(f));
}
__device__ __forceinline__ float bf2f(__bf16 b) {
    unsigned short s = __builtin_bit_cast(unsigned short, b);
    unsigned u = ((unsigned)s) << 16;
    return __builtin_bit_cast(float, u);
}

// ---------------- weight prep ----------------
__global__ __launch_bounds__(256) void k_wprep(
    const float* __restrict__ mW1, const float* __restrict__ mb1,
    const float* __restrict__ mW2, const float* __restrict__ pW1,
    const float* __restrict__ pb1, const float* __restrict__ pW2,
    const float* __restrict__ eW, const float* __restrict__ eb,
    const float* __restrict__ epW, const float* __restrict__ epb,
    const float* __restrict__ preW1, const float* __restrict__ preW2,
    unsigned short* __restrict__ W2T, unsigned short* __restrict__ pW2T,
    unsigned short* __restrict__ Wswz, float* __restrict__ biascat,
    unsigned short* __restrict__ WembSwz, float* __restrict__ biasemb,
    unsigned short* __restrict__ preW1T, unsigned short* __restrict__ preW2T)
{
    int idx = blockIdx.x * 256 + threadIdx.x;
    if (idx < 16384) {
        int l = idx >> 12, r = idx & 4095;
        int j = r >> 6, k = r & 63;
        int src = l * 4096 + k * 64 + j;
        W2T[idx] = f2bfu(mW2[src]);
        pW2T[idx] = f2bfu(pW2[src]);
    }
    if (idx < 131072) {
        int l = idx >> 15, rem = idx & 32767;
        int r = rem >> 7, k = rem & 127;
        const float* W1l = mW1 + (size_t)l * 16448;
        const float* pW1l = pW1 + (size_t)l * 8256;
        float v;
        if (r < 64)        v = W1l[k * 64 + r];
        else if (r < 128)  v = (k >= 64) ? pW1l[(k - 64) * 64 + (r - 64)] : 0.f;
        else if (r < 192)  v = W1l[(128 + k) * 64 + (r - 128)];
        else               v = (k >= 64) ? pW1l[k * 64 + (r - 192)] : 0.f;
        int c = k >> 3, e = k & 7;
        int cs = c ^ (r & 15);
        Wswz[(size_t)l * 32768 + r * 128 + cs * 8 + e] = f2bfu(v);
    }
    if (idx < 8192) {
        int r = idx >> 6, k = idx & 63;
        float v;
        if (r < 64) v = eW[k * 64 + r];
        else        v = (k >= 40) ? epW[(k - 40) * 64 + (r - 64)] : 0.f;
        int c = k >> 3, e = k & 7;
        int cs = c ^ (r & 7);
        WembSwz[r * 64 + cs * 8 + e] = f2bfu(v);
    }
    if (idx < 4096) {
        int j = idx >> 6, k = idx & 63;
        preW1T[idx] = f2bfu(preW1[k * 64 + j]);
        preW2T[idx] = f2bfu(preW2[k * 64 + j]);
    }
    if (idx < 1024) {
        int l = idx >> 8, col = idx & 255;
        float b = 0.f;
        if (col >= 128 && col < 192) b = mb1[l * 64 + col - 128];
        else if (col >= 192)         b = pb1[l * 64 + col - 192];
        biascat[idx] = b;
    }
    if (idx < 128) biasemb[idx] = (idx < 64) ? eb[idx] : epb[idx - 64];
}

// ---------------- counting sort by receiver (parallel scan) ----------------
__global__ void k_hist(const int* __restrict__ rec, int* __restrict__ hist)
{
    int e = blockIdx.x * 256 + threadIdx.x;
    if (e < NE) atomicAdd(&hist[rec[e]], 1);
}

__global__ __launch_bounds__(512) void k_scan1(const int* __restrict__ hist,
                                               int* __restrict__ cursor,
                                               int* __restrict__ bsum)
{
    __shared__ int ws[8];
    const int g = blockIdx.x * 512 + threadIdx.x;
    const int lane = threadIdx.x & 63, w = threadIdx.x >> 6;
    int v = (g < NN) ? hist[g] : 0;
    int inc = v;
#pragma unroll
    for (int d = 1; d < 64; d <<= 1) { int o = __shfl_up(inc, d); if (lane >= d) inc += o; }
    if (lane == 63) ws[w] = inc;
    __syncthreads();
    if (threadIdx.x < 8) {
        int x = ws[threadIdx.x];
        int p = x;
#pragma unroll
        for (int d = 1; d < 8; d <<= 1) { int o = __shfl_up(p, d); if ((int)threadIdx.x >= d) p += o; }
        ws[threadIdx.x] = p - x;
    }
    __syncthreads();
    if (g < NN) cursor[g] = ws[w] + inc - v;
    if (threadIdx.x == 511) bsum[blockIdx.x] = ws[7] + inc;
}

__global__ __launch_bounds__(128) void k_scan2(int* __restrict__ bsum)
{
    __shared__ int t0;
    const int i = threadIdx.x;
    const int lane = i & 63, w = i >> 6;
    int v = (i < 98) ? bsum[i] : 0;
    int inc = v;
#pragma unroll
    for (int d = 1; d < 64; d <<= 1) { int o = __shfl_up(inc, d); if (lane >= d) inc += o; }
    if (w == 0 && lane == 63) t0 = inc;
    __syncthreads();
    int ex = inc - v + (w ? t0 : 0);
    if (i < 98) bsum[i] = ex;
}

__global__ void k_scatter(const int* __restrict__ send, const int* __restrict__ rec,
                          const float* __restrict__ pos, int* __restrict__ cursor,
                          const int* __restrict__ boff,
                          int* __restrict__ ssend, int* __restrict__ srec,
                          float* __restrict__ sdist)
{
    int e = blockIdx.x * 256 + threadIdx.x;
    if (e >= NE) return;
    int s = send[e], r = rec[e];
    int p = atomicAdd(&cursor[r], 1) + boff[r >> 9];
    float dx = pos[s * 3 + 0] - pos[r * 3 + 0];
    float dy = pos[s * 3 + 1] - pos[r * 3 + 1];
    float dz = pos[s * 3 + 2] - pos[r * 3 + 2];
    ssend[p] = s; srec[p] = r;
    sdist[p] = sqrtf(dx * dx + dy * dy + dz * dz);
}

// ---------------- embed GEMM: [h|ph] = [x|pe] @ Wemb + bias ----------------
__global__ __launch_bounds__(256) void k_embed_gemm(
    const float* __restrict__ x, const float* __restrict__ pe,
    const unsigned short* __restrict__ Wswz, const float* __restrict__ bias,
    float* __restrict__ h, float* __restrict__ ph)
{
    __shared__ __align__(16) unsigned short wlds[8192];
    const int t = threadIdx.x;
    const int lane = t & 63, wv = t >> 6;
    const int l15 = lane & 15, q = lane >> 4;
    {
        const us8* src = (const us8*)Wswz;
        us8* dst = (us8*)wlds;
#pragma unroll
        for (int it = 0; it < 4; it++) dst[it * 256 + t] = src[it * 256 + t];
    }
    __syncthreads();

    const int NT = NN / 16;
    for (int tile = blockIdx.x * 4 + wv; tile < NT; tile += gridDim.x * 4) {
        const int rb = tile * 16;
        const int row = rb + l15;
        f32x4 uf[4];
        const float* p0 = x + (size_t)row * 40 + q * 8;
        const float* p1 = (q == 0) ? (x + (size_t)row * 40 + 32)
                                   : (pe + (size_t)row * 24 + (q - 1) * 8);
        uf[0] = *(const f32x4*)(p0);
        uf[1] = *(const f32x4*)(p0 + 4);
        uf[2] = *(const f32x4*)(p1);
        uf[3] = *(const f32x4*)(p1 + 4);
        bf16x8 af[2];
#pragma unroll
        for (int ks = 0; ks < 2; ks++)
#pragma unroll
            for (int i = 0; i < 4; i++) {
                af[ks][i]     = f2bf(uf[ks * 2][i]);
                af[ks][4 + i] = f2bf(uf[ks * 2 + 1][i]);
            }
        f32x4 acc[8];
#pragma unroll
        for (int jt = 0; jt < 8; jt++) acc[jt] = (f32x4){0.f, 0.f, 0.f, 0.f};
#pragma unroll
        for (int jt = 0; jt < 8; jt++) {
            int r = jt * 16 + l15;
#pragma unroll
            for (int ks = 0; ks < 2; ks++) {
                int c = (ks * 4 + q) ^ (l15 & 7);
                bf16x8 bfr = *(const bf16x8*)&wlds[r * 64 + c * 8];
                acc[jt] = __builtin_amdgcn_mfma_f32_16x16x32_bf16(af[ks], bfr, acc[jt], 0, 0, 0);
            }
        }
#pragma unroll
        for (int jt = 0; jt < 8; jt++) {
            int col = jt * 16 + l15;
            float bv = bias[col];
            float* outp = (jt < 4) ? (h + (size_t)(rb + q * 4) * 64 + col)
                                   : (ph + (size_t)(rb + q * 4) * 64 + (col - 64));
#pragma unroll
            for (int i = 0; i < 4; i++)
                outp[(size_t)i * 64] = acc[jt][i] + bv;
        }
    }
}

// ---------------- node GEMM: [stab|rtab](f16) = [h|ph] @ Wcat + bias; h2; ph2 ------
__global__ __launch_bounds__(256) void k_node_gemm(
    const float* __restrict__ h, const float* __restrict__ ph,
    const unsigned short* __restrict__ Wswz,
    const float* __restrict__ bias,
    _Float16* __restrict__ stab, _Float16* __restrict__ rtab,
    float* __restrict__ h2, float* __restrict__ ph2)
{
    __shared__ __align__(16) unsigned short wlds[32768];
    const int t = threadIdx.x;
    const int lane = t & 63, wv = t >> 6;
    const int l15 = lane & 15, q = lane >> 4;
    {
        const us8* src = (const us8*)Wswz;
        us8* dst = (us8*)wlds;
#pragma unroll
        for (int it = 0; it < 16; it++) dst[it * 256 + t] = src[it * 256 + t];
    }
    __syncthreads();

    const int NT = NN / 16;
    for (int tile = blockIdx.x * 4 + wv; tile < NT; tile += gridDim.x * 4) {
        const int rb = tile * 16;
        const int row = rb + l15;
        const float* hr = h + (size_t)row * 64;
        const float* pr = ph + (size_t)row * 64;
        f32x4 uf[8];
#pragma unroll
        for (int ks = 0; ks < 2; ks++) {
            uf[ks * 2 + 0] = *(const f32x4*)(hr + ks * 32 + q * 8);
            uf[ks * 2 + 1] = *(const f32x4*)(hr + ks * 32 + q * 8 + 4);
            uf[4 + ks * 2 + 0] = *(const f32x4*)(pr + ks * 32 + q * 8);
            uf[4 + ks * 2 + 1] = *(const f32x4*)(pr + ks * 32 + q * 8 + 4);
        }
        bf16x8 ahi[4], alo[4];
#pragma unroll
        for (int ks = 0; ks < 4; ks++)
#pragma unroll
            for (int i = 0; i < 4; i++) {
                float v0 = uf[ks * 2][i], v1 = uf[ks * 2 + 1][i];
                __bf16 h0 = f2bf(v0), h1 = f2bf(v1);
                ahi[ks][i] = h0; ahi[ks][4 + i] = h1;
                alo[ks][i] = f2bf(v0 - bf2f(h0));
                alo[ks][4 + i] = f2bf(v1 - bf2f(h1));
            }
        f32x4 acc[16];
#pragma unroll
        for (int jt = 0; jt < 16; jt++) acc[jt] = (f32x4){0.f, 0.f, 0.f, 0.f};
#pragma unroll
        for (int jt = 0; jt < 16; jt++) {
            int r = jt * 16 + l15;
#pragma unroll
            for (int ks = 0; ks < 4; ks++) {
                int c = (ks * 4 + q) ^ l15;
                bf16x8 bfr = *(const bf16x8*)&wlds[r * 128 + c * 8];
                acc[jt] = __builtin_amdgcn_mfma_f32_16x16x32_bf16(ahi[ks], bfr, acc[jt], 0, 0, 0);
                acc[jt] = __builtin_amdgcn_mfma_f32_16x16x32_bf16(alo[ks], bfr, acc[jt], 0, 0, 0);
            }
        }
#pragma unroll
        for (int jt = 0; jt < 16; jt++) {
            int col = jt * 16 + l15;
            float bv = bias[col];
            _Float16* outp = (jt < 8) ? (stab + (size_t)(rb + q * 4) * 128 + col)
                                      : (rtab + (size_t)(rb + q * 4) * 128 + (col - 128));
#pragma unroll
            for (int i = 0; i < 4; i++)
                outp[(size_t)i * 128] = (_Float16)(acc[jt][i] + bv);
        }
#pragma unroll
        for (int ks = 0; ks < 2; ks++) {
            *(f32x4*)(h2 + (size_t)row * 64 + ks * 32 + q * 8)     = uf[ks * 2] + uf[ks * 2];
            *(f32x4*)(h2 + (size_t)row * 64 + ks * 32 + q * 8 + 4) = uf[ks * 2 + 1] + uf[ks * 2 + 1];
            *(f32x4*)(ph2 + (size_t)row * 64 + ks * 32 + q * 8)     = uf[4 + ks * 2] + uf[4 + ks * 2];
            *(f32x4*)(ph2 + (size_t)row * 64 + ks * 32 + q * 8 + 4) = uf[4 + ks * 2 + 1] + uf[4 + ks * 2 + 1];
        }
    }
}

// ---------------- edge body: LDS-free, in-register segmented reduce ----------------
// Lane (q,l15): A/B fragment row = edge l15, k-cols q*8..+7. C-layout: lane holds
// m[edge q*4+i][feat jt*16+l15] -> its 4 edges are consecutive in sorted order, so
// the segmented reduce runs in registers; flushes are 64B-coalesced atomics.
template<int PATH>
__device__ __forceinline__ void edge_body(
    const int* __restrict__ ssend, const int* __restrict__ srec,
    const float* __restrict__ sdist,
    const _Float16* __restrict__ stb, const _Float16* __restrict__ rtb,
    const float* __restrict__ wrow, const unsigned short* __restrict__ w2,
    const float* __restrict__ b2p, float* __restrict__ outp,
    int chunk, int lane)
{
    const int l15 = lane & 15, q = lane >> 4;

    f32x4 w1c[4];
#pragma unroll
    for (int s = 0; s < 2; s++) {
        w1c[s * 2 + 0] = *(const f32x4*)(wrow + s * 32 + q * 8);
        w1c[s * 2 + 1] = *(const f32x4*)(wrow + s * 32 + q * 8 + 4);
    }
    bf16x8 wb[8];
#pragma unroll
    for (int jt = 0; jt < 4; jt++)
#pragma unroll
        for (int kk = 0; kk < 2; kk++) {
            int off = (jt * 16 + l15) * 64 + kk * 32 + q * 8;
            wb[jt * 2 + kk] = __builtin_bit_cast(bf16x8, *(const us8*)(w2 + off));
        }
    float b2v[4];
#pragma unroll
    for (int jt = 0; jt < 4; jt++) b2v[jt] = b2p[jt * 16 + l15];

    const int ebase = chunk * 64;
    int seA[4], reA[4]; float deA[4];
#pragma unroll
    for (int t = 0; t < 4; t++) {
        seA[t] = ssend[ebase + t * 16 + l15];
        reA[t] = srec[ebase + t * 16 + l15];
        deA[t] = sdist[ebase + t * 16 + l15];
    }

    half8 A[2], B[2];
    {
        const _Float16* sr = stb + (size_t)seA[0] * 128;
        const _Float16* rr = rtb + (size_t)reA[0] * 128;
#pragma unroll
        for (int s = 0; s < 2; s++) {
            A[s] = *(const half8*)(sr + s * 32 + q * 8);
            B[s] = *(const half8*)(rr + s * 32 + q * 8);
        }
    }

#pragma unroll
    for (int t = 0; t < 4; t++) {
        // receivers of this lane's 4 output edges (uniform per 16-lane q-group)
        int4 rq = *(const int4*)(srec + ebase + t * 16 + q * 4);

        half8 An[2], Bn[2];
        if (t < 3) {
            const _Float16* sr = stb + (size_t)seA[t + 1] * 128;
            const _Float16* rr = rtb + (size_t)reA[t + 1] * 128;
#pragma unroll
            for (int s = 0; s < 2; s++) {
                An[s] = *(const half8*)(sr + s * 32 + q * 8);
                Bn[s] = *(const half8*)(rr + s * 32 + q * 8);
            }
        }

        const float de = deA[t];
        bf16x8 ah[2];
#pragma unroll
        for (int s = 0; s < 2; s++)
#pragma unroll
            for (int i = 0; i < 4; i++) {
                float v0 = (float)A[s][i]     + (float)B[s][i]     + de * w1c[s * 2][i];
                float v1 = (float)A[s][4 + i] + (float)B[s][4 + i] + de * w1c[s * 2 + 1][i];
                ah[s][i]     = f2bf(PATH ? tanh_f(v0) : silu_f(v0));
                ah[s][4 + i] = f2bf(PATH ? tanh_f(v1) : silu_f(v1));
            }
        f32x4 accs[4];
#pragma unroll
        for (int jt = 0; jt < 4; jt++) {
            f32x4 acc = {0.f, 0.f, 0.f, 0.f};
            acc = __builtin_amdgcn_mfma_f32_16x16x32_bf16(ah[0], wb[jt * 2 + 0], acc, 0, 0, 0);
            acc = __builtin_amdgcn_mfma_f32_16x16x32_bf16(ah[1], wb[jt * 2 + 1], acc, 0, 0, 0);
            accs[jt] = acc;
        }

        // in-register segmented reduce over the lane's 4 sorted edges
        float s4[4];
        int rcur = rq.x;
#pragma unroll
        for (int jt = 0; jt < 4; jt++) {
            float m = accs[jt][0] + b2v[jt];
            s4[jt] = PATH ? tanh_f(m) : silu_f(m);
        }
        const int rnx[3] = {rq.y, rq.z, rq.w};
#pragma unroll
        for (int i = 1; i < 4; i++) {
            int ri = rnx[i - 1];
            bool nb = (ri != rcur);
            if (nb) {
#pragma unroll
                for (int jt = 0; jt < 4; jt++)
                    atomicAdd(&outp[(size_t)rcur * 64 + jt * 16 + l15], s4[jt]);
            }
#pragma unroll
            for (int jt = 0; jt < 4; jt++) {
                float m = accs[jt][i] + b2v[jt];
                float v = PATH ? tanh_f(m) : silu_f(m);
                s4[jt] = nb ? v : (s4[jt] + v);
            }
            rcur = ri;
        }
#pragma unroll
        for (int jt = 0; jt < 4; jt++)
            atomicAdd(&outp[(size_t)rcur * 64 + jt * 16 + l15], s4[jt]);

        if (t < 3) {
#pragma unroll
            for (int s = 0; s < 2; s++) { A[s] = An[s]; B[s] = Bn[s]; }
        }
    }
}

// one dispatch covers both paths: blockIdx.y = 0 (h/silu) or 1 (pe/tanh)
__global__ __launch_bounds__(256, 3) void k_edge2(
    const int* __restrict__ ssend, const int* __restrict__ srec,
    const float* __restrict__ sdist,
    const _Float16* __restrict__ stab, const _Float16* __restrict__ rtab,
    const float* __restrict__ mW1, const float* __restrict__ mb2,
    const float* __restrict__ pW1g, const float* __restrict__ pb2,
    const unsigned short* __restrict__ W2T, const unsigned short* __restrict__ pW2T,
    int layer,
    float* __restrict__ hout, float* __restrict__ pout)
{
    const int lane = threadIdx.x & 63;
    const int wv = threadIdx.x >> 6;
    const int chunk = (blockIdx.x << 2) + wv;
    if (chunk >= NE / 64) return;
    if (blockIdx.y == 0)
        edge_body<0>(ssend, srec, sdist, stab, rtab,
                     mW1 + (size_t)layer * 16448 + 16384,
                     W2T + layer * 4096, mb2 + layer * 64, hout, chunk, lane);
    else
        edge_body<1>(ssend, srec, sdist, stab + 64, rtab + 64,
                     pW1g + (size_t)layer * 8256 + 8192,
                     pW2T + layer * 4096, pb2 + layer * 64, pout, chunk, lane);
}

// ---------------- final node MLP + pooling (MFMA + segmented flush) ----------------
__global__ __launch_bounds__(256) void k_prepool(
    const float* __restrict__ h, const int* __restrict__ batch,
    const unsigned short* __restrict__ preW1T, const float* __restrict__ b1,
    const unsigned short* __restrict__ preW2T, const float* __restrict__ b2,
    float* __restrict__ pooled)
{
    __shared__ __align__(16) float tl[4][16][68];
    const int lane = threadIdx.x & 63;
    const int wv = threadIdx.x >> 6;
    const int l15 = lane & 15, q = lane >> 4;

    bf16x8 wb1[8], wb2[8];
#pragma unroll
    for (int jt = 0; jt < 4; jt++)
#pragma unroll
        for (int kk = 0; kk < 2; kk++) {
            int off = (jt * 16 + l15) * 64 + kk * 32 + q * 8;
            wb1[jt * 2 + kk] = __builtin_bit_cast(bf16x8, *(const us8*)(preW1T + off));
            wb2[jt * 2 + kk] = __builtin_bit_cast(bf16x8, *(const us8*)(preW2T + off));
        }
    float b1v[4], b2v[4];
#pragma unroll
    for (int jt = 0; jt < 4; jt++) {
        b1v[jt] = b1[jt * 16 + l15];
        b2v[jt] = b2[jt * 16 + l15];
    }

    const int NT = NN / 16;
    for (int tile = blockIdx.x * 4 + wv; tile < NT; tile += gridDim.x * 4) {
        const int rb = tile * 16;
        const int row = rb + l15;
        const int gidl = batch[row];
        const float* hr = h + (size_t)row * 64;
        f32x4 uf[4];
#pragma unroll
        for (int ks = 0; ks < 2; ks++) {
            uf[ks * 2 + 0] = *(const f32x4*)(hr + ks * 32 + q * 8);
            uf[ks * 2 + 1] = *(const f32x4*)(hr + ks * 32 + q * 8 + 4);
        }
        bf16x8 ahi[2], alo[2];
#pragma unroll
        for (int ks = 0; ks < 2; ks++)
#pragma unroll
            for (int i = 0; i < 4; i++) {
                float v0 = uf[ks * 2][i], v1 = uf[ks * 2 + 1][i];
                __bf16 h0 = f2bf(v0), h1 = f2bf(v1);
                ahi[ks][i] = h0; ahi[ks][4 + i] = h1;
                alo[ks][i] = f2bf(v0 - bf2f(h0));
                alo[ks][4 + i] = f2bf(v1 - bf2f(h1));
            }
#pragma unroll
        for (int jt = 0; jt < 4; jt++) {
            f32x4 acc = {0.f, 0.f, 0.f, 0.f};
#pragma unroll
            for (int ks = 0; ks < 2; ks++) {
                acc = __builtin_amdgcn_mfma_f32_16x16x32_bf16(ahi[ks], wb1[jt * 2 + ks], acc, 0, 0, 0);
                acc = __builtin_amdgcn_mfma_f32_16x16x32_bf16(alo[ks], wb1[jt * 2 + ks], acc, 0, 0, 0);
            }
#pragma unroll
            for (int i = 0; i < 4; i++)
                tl[wv][q * 4 + i][jt * 16 + l15] = silu_f(acc[i] + b1v[jt]);
        }
        const float* tr = &tl[wv][l15][0];
        f32x4 u0 = *(const f32x4*)(tr + q * 8);
        f32x4 u1 = *(const f32x4*)(tr + q * 8 + 4);
        f32x4 u2 = *(const f32x4*)(tr + 32 + q * 8);
        f32x4 u3 = *(const f32x4*)(tr + 32 + q * 8 + 4);
        bf16x8 thi[2], tlo[2];
#pragma unroll
        for (int i = 0; i < 4; i++) {
            __bf16 c0 = f2bf(u0[i]), c1 = f2bf(u1[i]), c2 = f2bf(u2[i]), c3 = f2bf(u3[i]);
            thi[0][i] = c0; thi[0][4 + i] = c1; thi[1][i] = c2; thi[1][4 + i] = c3;
            tlo[0][i] = f2bf(u0[i] - bf2f(c0)); tlo[0][4 + i] = f2bf(u1[i] - bf2f(c1));
            tlo[1][i] = f2bf(u2[i] - bf2f(c2)); tlo[1][4 + i] = f2bf(u3[i] - bf2f(c3));
        }
#pragma unroll
        for (int jt = 0; jt < 4; jt++) {
            f32x4 acc = {0.f, 0.f, 0.f, 0.f};
#pragma unroll
            for (int ks = 0; ks < 2; ks++) {
                acc = __builtin_amdgcn_mfma_f32_16x16x32_bf16(thi[ks], wb2[jt * 2 + ks], acc, 0, 0, 0);
                acc = __builtin_amdgcn_mfma_f32_16x16x32_bf16(tlo[ks], wb2[jt * 2 + ks], acc, 0, 0, 0);
            }
#pragma unroll
            for (int i = 0; i < 4; i++)
                tl[wv][q * 4 + i][jt * 16 + l15] = acc[i] + b2v[jt];
        }
        float vh[16];
#pragma unroll
        for (int e = 0; e < 16; e++) vh[e] = tl[wv][e][lane];
        float acc1 = 0.f;
        int cur = -1;
#pragma unroll
        for (int e = 0; e < 16; e++) {
            int ge = __shfl(gidl, e);
            if (ge != cur) {
                if (cur >= 0) atomicAdd(&pooled[(size_t)cur * 64 + lane], acc1);
                cur = ge; acc1 = 0.f;
            }
            acc1 += vh[e];
        }
        if (cur >= 0) atomicAdd(&pooled[(size_t)cur * 64 + lane], acc1);
    }
}

// ---------------- readout ----------------
__global__ __launch_bounds__(256) void k_readout(
    const float* __restrict__ pooled,
    const float* __restrict__ W1, const float* __restrict__ b1,
    const float* __restrict__ W2, const float* __restrict__ b2,
    float* __restrict__ out)
{
    const int lane = threadIdx.x & 63;
    const int wv = threadIdx.x >> 6;
    const int g = (blockIdx.x << 2) + wv;
    if (g >= NG) return;
    const float* pr = pooled + (size_t)g * 64;
    float a0 = 0, a1 = 0, a2 = 0, a3 = 0;
#pragma unroll
    for (int k = 0; k < 64; k += 4) {
        a0 += pr[k] * W1[k * 64 + lane]; a1 += pr[k + 1] * W1[(k + 1) * 64 + lane];
        a2 += pr[k + 2] * W1[(k + 2) * 64 + lane]; a3 += pr[k + 3] * W1[(k + 3) * 64 + lane];
    }
    float v = silu_f(a0 + a1 + a2 + a3 + b1[lane]) * W2[lane];
#pragma unroll
    for (int off = 32; off > 0; off >>= 1) v += __shfl_down(v, off);
    if (lane == 0) out[g] = v + b2[0];
}

extern "C" void kernel_launch(void* const* d_in, const int* in_sizes, int n_in,
                              void* d_out, int out_size, void* d_ws, size_t ws_size,
                              hipStream_t stream)
{
    const float* x = (const float*)d_in[0];
    const float* pos = (const float*)d_in[1];
    const float* pe = (const float*)d_in[2];
    const int* eidx = (const int*)d_in[3];
    const int* batch = (const int*)d_in[4];
    const float* eW = (const float*)d_in[5];
    const float* eb = (const float*)d_in[6];
    const float* epW = (const float*)d_in[7];
    const float* epb = (const float*)d_in[8];
    const float* mW1 = (const float*)d_in[9];
    const float* mb1 = (const float*)d_in[10];
    const float* mW2 = (const float*)d_in[11];
    const float* mb2 = (const float*)d_in[12];
    const float* pW1 = (const float*)d_in[13];
    const float* pb1 = (const float*)d_in[14];
    const float* pW2 = (const float*)d_in[15];
    const float* pb2 = (const float*)d_in[16];
    const float* preW1 = (const float*)d_in[17];
    const float* preb1 = (const float*)d_in[18];
    const float* preW2 = (const float*)d_in[19];
    const float* preb2 = (const float*)d_in[20];
    const float* roW1 = (const float*)d_in[21];
    const float* rob1 = (const float*)d_in[22];
    const float* roW2 = (const float*)d_in[23];
    const float* rob2 = (const float*)d_in[24];

    const int* send = eidx;
    const int* rcv = eidx + NE;

    float* f = (float*)d_ws;
    size_t o = 0;
    float* hA = f + o; o += (size_t)NN * 64;
    float* hB = f + o; o += (size_t)NN * 64;
    float* phA = f + o; o += (size_t)NN * 64;
    float* phB = f + o; o += (size_t)NN * 64;
    _Float16* stab = (_Float16*)(f + o); o += (size_t)NN * 64;
    _Float16* rtab = (_Float16*)(f + o); o += (size_t)NN * 64;
    float* pooled = f + o; o += NG * 64;
    unsigned short* W2T = (unsigned short*)(f + o); o += 8192;
    unsigned short* pW2T = (unsigned short*)(f + o); o += 8192;
    unsigned short* Wswz = (unsigned short*)(f + o); o += 65536;
    unsigned short* WembSwz = (unsigned short*)(f + o); o += 4096;
    unsigned short* preW1T = (unsigned short*)(f + o); o += 2048;
    unsigned short* preW2T = (unsigned short*)(f + o); o += 2048;
    float* biascat = f + o; o += 1024;
    float* biasemb = f + o; o += 128;
    int* hist = (int*)(f + o); o += NN;
    int* cursor = (int*)(f + o); o += NN;
    int* bsum = (int*)(f + o); o += 128;
    int* ssend = (int*)(f + o); o += NE;
    int* srec = (int*)(f + o); o += NE;
    float* sdist = f + o; o += NE;

    hipMemsetAsync(pooled, 0, NG * 64 * sizeof(float), stream);
    hipMemsetAsync(hist, 0, NN * sizeof(int), stream);
    k_wprep<<<512, 256, 0, stream>>>(mW1, mb1, mW2, pW1, pb1, pW2,
                                     eW, eb, epW, epb, preW1, preW2,
                                     W2T, pW2T, Wswz, biascat, WembSwz, biasemb,
                                     preW1T, preW2T);
    k_hist<<<(NE + 255) / 256, 256, 0, stream>>>(rcv, hist);
    k_scan1<<<98, 512, 0, stream>>>(hist, cursor, bsum);
    k_scan2<<<1, 128, 0, stream>>>(bsum);
    k_scatter<<<(NE + 255) / 256, 256, 0, stream>>>(send, rcv, pos, cursor, bsum,
                                                    ssend, srec, sdist);
    k_embed_gemm<<<512, 256, 0, stream>>>(x, pe, WembSwz, biasemb, hA, phA);

    const int EB = (NE / 64 + 3) / 4;
    float* hin = hA; float* pin = phA; float* hout = hB; float* pout = phB;
    for (int l = 0; l < 4; l++) {
        k_node_gemm<<<512, 256, 0, stream>>>(hin, pin, Wswz + (size_t)l * 32768,
                                             biascat + l * 256, stab, rtab, hout, pout);
        k_edge2<<<dim3(EB, 2), 256, 0, stream>>>(ssend, srec, sdist, stab, rtab,
                                                 mW1, mb2, pW1, pb2, W2T, pW2T, l,
                                                 hout, pout);
        float* t;
        t = hin; hin = hout; hout = t;
        t = pin; pin = pout; pout = t;
    }
    k_prepool<<<512, 256, 0, stream>>>(hin, batch, preW1T, preb1, preW2T, preb2, pooled);
    k_readout<<<128, 256, 0, stream>>>(pooled, roW1, rob1, roW2, rob2, (float*)d_out);
}

// Round 10
// 380.796 us; speedup vs baseline: 1.7678x; 1.7678x over previous
//
#include <hip/hip_runtime.h>

#define NN 50000
#define NE 400000
#define NG 512

typedef __bf16 bf16x8 __attribute__((ext_vector_type(8)));
typedef float f32x4 __attribute__((ext_vector_type(4)));
typedef unsigned short us8 __attribute__((ext_vector_type(8)));
typedef _Float16 half8 __attribute__((ext_vector_type(8)));

__device__ __forceinline__ float frcp(float x) { return __builtin_amdgcn_rcpf(x); }
__device__ __forceinline__ float silu_f(float x) { return x * frcp(1.f + __expf(-x)); }
__device__ __forceinline__ float tanh_f(float x) { return 1.f - 2.f * frcp(__expf(2.f * x) + 1.f); }
__device__ __forceinline__ __bf16 f2bf(float f) {
    unsigned u = __builtin_bit_cast(unsigned, f);
    u += 0x7fffu + ((u >> 16) & 1u);
    unsigned short s = (unsigned short)(u >> 16);
    return __builtin_bit_cast(__bf16, s);
}
__device__ __forceinline__ unsigned short f2bfu(float f) {
    return __builtin_bit_cast(unsigned short, f2bf(f));
}
__device__ __forceinline__ float bf2f(__bf16 b) {
    unsigned short s = __builtin_bit_cast(unsigned short, b);
    unsigned u = ((unsigned)s) << 16;
    return __builtin_bit_cast(float, u);
}

// ---------------- weight prep ----------------
__global__ __launch_bounds__(256) void k_wprep(
    const float* __restrict__ mW1, const float* __restrict__ mb1,
    const float* __restrict__ mW2, const float* __restrict__ pW1,
    const float* __restrict__ pb1, const float* __restrict__ pW2,
    const float* __restrict__ eW, const float* __restrict__ eb,
    const float* __restrict__ epW, const float* __restrict__ epb,
    const float* __restrict__ preW1, const float* __restrict__ preW2,
    unsigned short* __restrict__ W2T, unsigned short* __restrict__ pW2T,
    unsigned short* __restrict__ Wswz, float* __restrict__ biascat,
    unsigned short* __restrict__ WembSwz, float* __restrict__ biasemb,
    unsigned short* __restrict__ preW1T, unsigned short* __restrict__ preW2T)
{
    int idx = blockIdx.x * 256 + threadIdx.x;
    if (idx < 16384) {
        int l = idx >> 12, r = idx & 4095;
        int j = r >> 6, k = r & 63;
        int src = l * 4096 + k * 64 + j;
        W2T[idx] = f2bfu(mW2[src]);
        pW2T[idx] = f2bfu(pW2[src]);
    }
    if (idx < 131072) {
        int l = idx >> 15, rem = idx & 32767;
        int r = rem >> 7, k = rem & 127;
        const float* W1l = mW1 + (size_t)l * 16448;
        const float* pW1l = pW1 + (size_t)l * 8256;
        float v;
        if (r < 64)        v = W1l[k * 64 + r];
        else if (r < 128)  v = (k >= 64) ? pW1l[(k - 64) * 64 + (r - 64)] : 0.f;
        else if (r < 192)  v = W1l[(128 + k) * 64 + (r - 128)];
        else               v = (k >= 64) ? pW1l[k * 64 + (r - 192)] : 0.f;
        int c = k >> 3, e = k & 7;
        int cs = c ^ (r & 15);
        Wswz[(size_t)l * 32768 + r * 128 + cs * 8 + e] = f2bfu(v);
    }
    if (idx < 8192) {
        int r = idx >> 6, k = idx & 63;
        float v;
        if (r < 64) v = eW[k * 64 + r];
        else        v = (k >= 40) ? epW[(k - 40) * 64 + (r - 64)] : 0.f;
        int c = k >> 3, e = k & 7;
        int cs = c ^ (r & 7);
        WembSwz[r * 64 + cs * 8 + e] = f2bfu(v);
    }
    if (idx < 4096) {
        int j = idx >> 6, k = idx & 63;
        preW1T[idx] = f2bfu(preW1[k * 64 + j]);
        preW2T[idx] = f2bfu(preW2[k * 64 + j]);
    }
    if (idx < 1024) {
        int l = idx >> 8, col = idx & 255;
        float b = 0.f;
        if (col >= 128 && col < 192) b = mb1[l * 64 + col - 128];
        else if (col >= 192)         b = pb1[l * 64 + col - 192];
        biascat[idx] = b;
    }
    if (idx < 128) biasemb[idx] = (idx < 64) ? eb[idx] : epb[idx - 64];
}

// ---------------- counting sort by receiver (parallel scan) ----------------
__global__ void k_hist(const int* __restrict__ rec, int* __restrict__ hist)
{
    int e = blockIdx.x * 256 + threadIdx.x;
    if (e < NE) atomicAdd(&hist[rec[e]], 1);
}

__global__ __launch_bounds__(512) void k_scan1(const int* __restrict__ hist,
                                               int* __restrict__ cursor,
                                               int* __restrict__ bsum)
{
    __shared__ int ws[8];
    const int g = blockIdx.x * 512 + threadIdx.x;
    const int lane = threadIdx.x & 63, w = threadIdx.x >> 6;
    int v = (g < NN) ? hist[g] : 0;
    int inc = v;
#pragma unroll
    for (int d = 1; d < 64; d <<= 1) { int o = __shfl_up(inc, d); if (lane >= d) inc += o; }
    if (lane == 63) ws[w] = inc;
    __syncthreads();
    if (threadIdx.x < 8) {
        int x = ws[threadIdx.x];
        int p = x;
#pragma unroll
        for (int d = 1; d < 8; d <<= 1) { int o = __shfl_up(p, d); if ((int)threadIdx.x >= d) p += o; }
        ws[threadIdx.x] = p - x;
    }
    __syncthreads();
    if (g < NN) cursor[g] = ws[w] + inc - v;
    if (threadIdx.x == 511) bsum[blockIdx.x] = ws[7] + inc;
}

__global__ __launch_bounds__(128) void k_scan2(int* __restrict__ bsum)
{
    __shared__ int t0;
    const int i = threadIdx.x;
    const int lane = i & 63, w = i >> 6;
    int v = (i < 98) ? bsum[i] : 0;
    int inc = v;
#pragma unroll
    for (int d = 1; d < 64; d <<= 1) { int o = __shfl_up(inc, d); if (lane >= d) inc += o; }
    if (w == 0 && lane == 63) t0 = inc;
    __syncthreads();
    int ex = inc - v + (w ? t0 : 0);
    if (i < 98) bsum[i] = ex;
}

__global__ void k_scatter(const int* __restrict__ send, const int* __restrict__ rec,
                          const float* __restrict__ pos, int* __restrict__ cursor,
                          const int* __restrict__ boff,
                          int* __restrict__ ssend, int* __restrict__ srec,
                          float* __restrict__ sdist)
{
    int e = blockIdx.x * 256 + threadIdx.x;
    if (e >= NE) return;
    int s = send[e], r = rec[e];
    int p = atomicAdd(&cursor[r], 1) + boff[r >> 9];
    float dx = pos[s * 3 + 0] - pos[r * 3 + 0];
    float dy = pos[s * 3 + 1] - pos[r * 3 + 1];
    float dz = pos[s * 3 + 2] - pos[r * 3 + 2];
    ssend[p] = s; srec[p] = r;
    sdist[p] = sqrtf(dx * dx + dy * dy + dz * dz);
}

// ---------------- embed GEMM: [h|ph] = [x|pe] @ Wemb + bias ----------------
__global__ __launch_bounds__(256) void k_embed_gemm(
    const float* __restrict__ x, const float* __restrict__ pe,
    const unsigned short* __restrict__ Wswz, const float* __restrict__ bias,
    float* __restrict__ h, float* __restrict__ ph)
{
    __shared__ __align__(16) unsigned short wlds[8192];
    const int t = threadIdx.x;
    const int lane = t & 63, wv = t >> 6;
    const int l15 = lane & 15, q = lane >> 4;
    {
        const us8* src = (const us8*)Wswz;
        us8* dst = (us8*)wlds;
#pragma unroll
        for (int it = 0; it < 4; it++) dst[it * 256 + t] = src[it * 256 + t];
    }
    __syncthreads();

    const int NT = NN / 16;
    for (int tile = blockIdx.x * 4 + wv; tile < NT; tile += gridDim.x * 4) {
        const int rb = tile * 16;
        const int row = rb + l15;
        f32x4 uf[4];
        const float* p0 = x + (size_t)row * 40 + q * 8;
        const float* p1 = (q == 0) ? (x + (size_t)row * 40 + 32)
                                   : (pe + (size_t)row * 24 + (q - 1) * 8);
        uf[0] = *(const f32x4*)(p0);
        uf[1] = *(const f32x4*)(p0 + 4);
        uf[2] = *(const f32x4*)(p1);
        uf[3] = *(const f32x4*)(p1 + 4);
        bf16x8 af[2];
#pragma unroll
        for (int ks = 0; ks < 2; ks++)
#pragma unroll
            for (int i = 0; i < 4; i++) {
                af[ks][i]     = f2bf(uf[ks * 2][i]);
                af[ks][4 + i] = f2bf(uf[ks * 2 + 1][i]);
            }
        f32x4 acc[8];
#pragma unroll
        for (int jt = 0; jt < 8; jt++) acc[jt] = (f32x4){0.f, 0.f, 0.f, 0.f};
#pragma unroll
        for (int jt = 0; jt < 8; jt++) {
            int r = jt * 16 + l15;
#pragma unroll
            for (int ks = 0; ks < 2; ks++) {
                int c = (ks * 4 + q) ^ (l15 & 7);
                bf16x8 bfr = *(const bf16x8*)&wlds[r * 64 + c * 8];
                acc[jt] = __builtin_amdgcn_mfma_f32_16x16x32_bf16(af[ks], bfr, acc[jt], 0, 0, 0);
            }
        }
#pragma unroll
        for (int jt = 0; jt < 8; jt++) {
            int col = jt * 16 + l15;
            float bv = bias[col];
            float* outp = (jt < 4) ? (h + (size_t)(rb + q * 4) * 64 + col)
                                   : (ph + (size_t)(rb + q * 4) * 64 + (col - 64));
#pragma unroll
            for (int i = 0; i < 4; i++)
                outp[(size_t)i * 64] = acc[jt][i] + bv;
        }
    }
}

// ---------------- node GEMM: [stab|rtab](f16) = [h|ph] @ Wcat + bias; h2; ph2 ------
__global__ __launch_bounds__(256) void k_node_gemm(
    const float* __restrict__ h, const float* __restrict__ ph,
    const unsigned short* __restrict__ Wswz,
    const float* __restrict__ bias,
    _Float16* __restrict__ stab, _Float16* __restrict__ rtab,
    float* __restrict__ h2, float* __restrict__ ph2)
{
    __shared__ __align__(16) unsigned short wlds[32768];
    const int t = threadIdx.x;
    const int lane = t & 63, wv = t >> 6;
    const int l15 = lane & 15, q = lane >> 4;
    {
        const us8* src = (const us8*)Wswz;
        us8* dst = (us8*)wlds;
#pragma unroll
        for (int it = 0; it < 16; it++) dst[it * 256 + t] = src[it * 256 + t];
    }
    __syncthreads();

    const int NT = NN / 16;
    for (int tile = blockIdx.x * 4 + wv; tile < NT; tile += gridDim.x * 4) {
        const int rb = tile * 16;
        const int row = rb + l15;
        const float* hr = h + (size_t)row * 64;
        const float* pr = ph + (size_t)row * 64;
        f32x4 uf[8];
#pragma unroll
        for (int ks = 0; ks < 2; ks++) {
            uf[ks * 2 + 0] = *(const f32x4*)(hr + ks * 32 + q * 8);
            uf[ks * 2 + 1] = *(const f32x4*)(hr + ks * 32 + q * 8 + 4);
            uf[4 + ks * 2 + 0] = *(const f32x4*)(pr + ks * 32 + q * 8);
            uf[4 + ks * 2 + 1] = *(const f32x4*)(pr + ks * 32 + q * 8 + 4);
        }
        bf16x8 ahi[4], alo[4];
#pragma unroll
        for (int ks = 0; ks < 4; ks++)
#pragma unroll
            for (int i = 0; i < 4; i++) {
                float v0 = uf[ks * 2][i], v1 = uf[ks * 2 + 1][i];
                __bf16 h0 = f2bf(v0), h1 = f2bf(v1);
                ahi[ks][i] = h0; ahi[ks][4 + i] = h1;
                alo[ks][i] = f2bf(v0 - bf2f(h0));
                alo[ks][4 + i] = f2bf(v1 - bf2f(h1));
            }
        f32x4 acc[16];
#pragma unroll
        for (int jt = 0; jt < 16; jt++) acc[jt] = (f32x4){0.f, 0.f, 0.f, 0.f};
#pragma unroll
        for (int jt = 0; jt < 16; jt++) {
            int r = jt * 16 + l15;
#pragma unroll
            for (int ks = 0; ks < 4; ks++) {
                int c = (ks * 4 + q) ^ l15;
                bf16x8 bfr = *(const bf16x8*)&wlds[r * 128 + c * 8];
                acc[jt] = __builtin_amdgcn_mfma_f32_16x16x32_bf16(ahi[ks], bfr, acc[jt], 0, 0, 0);
                acc[jt] = __builtin_amdgcn_mfma_f32_16x16x32_bf16(alo[ks], bfr, acc[jt], 0, 0, 0);
            }
        }
#pragma unroll
        for (int jt = 0; jt < 16; jt++) {
            int col = jt * 16 + l15;
            float bv = bias[col];
            _Float16* outp = (jt < 8) ? (stab + (size_t)(rb + q * 4) * 128 + col)
                                      : (rtab + (size_t)(rb + q * 4) * 128 + (col - 128));
#pragma unroll
            for (int i = 0; i < 4; i++)
                outp[(size_t)i * 128] = (_Float16)(acc[jt][i] + bv);
        }
#pragma unroll
        for (int ks = 0; ks < 2; ks++) {
            *(f32x4*)(h2 + (size_t)row * 64 + ks * 32 + q * 8)     = uf[ks * 2] + uf[ks * 2];
            *(f32x4*)(h2 + (size_t)row * 64 + ks * 32 + q * 8 + 4) = uf[ks * 2 + 1] + uf[ks * 2 + 1];
            *(f32x4*)(ph2 + (size_t)row * 64 + ks * 32 + q * 8)     = uf[4 + ks * 2] + uf[4 + ks * 2];
            *(f32x4*)(ph2 + (size_t)row * 64 + ks * 32 + q * 8 + 4) = uf[4 + ks * 2 + 1] + uf[4 + ks * 2 + 1];
        }
    }
}

// ---------------- edge body (round-8 proven): LDS-scan segmented reduce ------------
template<int PATH>
__device__ __forceinline__ void edge_body(
    const int* __restrict__ ssend, const int* __restrict__ srec,
    const float* __restrict__ sdist,
    const _Float16* __restrict__ stb, const _Float16* __restrict__ rtb,
    const float* __restrict__ wrow, const unsigned short* __restrict__ w2,
    const float* __restrict__ b2p, float* __restrict__ outp,
    int chunk, int lane, float (*mbuf)[68])
{
    const int l15 = lane & 15, q = lane >> 4;

    f32x4 w1c[4];
#pragma unroll
    for (int s = 0; s < 2; s++) {
        w1c[s * 2 + 0] = *(const f32x4*)(wrow + s * 32 + q * 8);
        w1c[s * 2 + 1] = *(const f32x4*)(wrow + s * 32 + q * 8 + 4);
    }
    bf16x8 wb[8];
#pragma unroll
    for (int jt = 0; jt < 4; jt++)
#pragma unroll
        for (int kk = 0; kk < 2; kk++) {
            int off = (jt * 16 + l15) * 64 + kk * 32 + q * 8;
            wb[jt * 2 + kk] = __builtin_bit_cast(bf16x8, *(const us8*)(w2 + off));
        }
    float b2v[4];
#pragma unroll
    for (int jt = 0; jt < 4; jt++) b2v[jt] = b2p[jt * 16 + l15];

    const int ebase = chunk * 64;
    int seA[4], reA[4]; float deA[4];
#pragma unroll
    for (int t = 0; t < 4; t++) {
        seA[t] = ssend[ebase + t * 16 + l15];
        reA[t] = srec[ebase + t * 16 + l15];
        deA[t] = sdist[ebase + t * 16 + l15];
    }

    half8 A[2], B[2];
    {
        const _Float16* sr = stb + (size_t)seA[0] * 128;
        const _Float16* rr = rtb + (size_t)reA[0] * 128;
#pragma unroll
        for (int s = 0; s < 2; s++) {
            A[s] = *(const half8*)(sr + s * 32 + q * 8);
            B[s] = *(const half8*)(rr + s * 32 + q * 8);
        }
    }

    float acc1 = 0.f;
    int cur = -1;

#pragma unroll
    for (int t = 0; t < 4; t++) {
        half8 An[2], Bn[2];
        if (t < 3) {
            const _Float16* sr = stb + (size_t)seA[t + 1] * 128;
            const _Float16* rr = rtb + (size_t)reA[t + 1] * 128;
#pragma unroll
            for (int s = 0; s < 2; s++) {
                An[s] = *(const half8*)(sr + s * 32 + q * 8);
                Bn[s] = *(const half8*)(rr + s * 32 + q * 8);
            }
        }

        const float de = deA[t];
        bf16x8 ah[2];
#pragma unroll
        for (int s = 0; s < 2; s++)
#pragma unroll
            for (int i = 0; i < 4; i++) {
                float v0 = (float)A[s][i]     + (float)B[s][i]     + de * w1c[s * 2][i];
                float v1 = (float)A[s][4 + i] + (float)B[s][4 + i] + de * w1c[s * 2 + 1][i];
                ah[s][i]     = f2bf(PATH ? tanh_f(v0) : silu_f(v0));
                ah[s][4 + i] = f2bf(PATH ? tanh_f(v1) : silu_f(v1));
            }
#pragma unroll
        for (int jt = 0; jt < 4; jt++) {
            f32x4 acc = {0.f, 0.f, 0.f, 0.f};
            acc = __builtin_amdgcn_mfma_f32_16x16x32_bf16(ah[0], wb[jt * 2 + 0], acc, 0, 0, 0);
            acc = __builtin_amdgcn_mfma_f32_16x16x32_bf16(ah[1], wb[jt * 2 + 1], acc, 0, 0, 0);
#pragma unroll
            for (int i = 0; i < 4; i++) {
                float m = acc[i] + b2v[jt];
                mbuf[q * 4 + i][jt * 16 + l15] = PATH ? tanh_f(m) : silu_f(m);
            }
        }

        float vh[16];
#pragma unroll
        for (int e = 0; e < 16; e++) vh[e] = mbuf[e][lane];
#pragma unroll
        for (int e = 0; e < 16; e++) {
            int ree = __shfl(reA[t], e);
            if (ree != cur) {
                if (cur >= 0) atomicAdd(&outp[(size_t)cur * 64 + lane], acc1);
                cur = ree; acc1 = 0.f;
            }
            acc1 += vh[e];
        }

        if (t < 3) {
#pragma unroll
            for (int s = 0; s < 2; s++) { A[s] = An[s]; B[s] = Bn[s]; }
        }
    }
    if (cur >= 0) atomicAdd(&outp[(size_t)cur * 64 + lane], acc1);
}

// one dispatch covers both paths: blockIdx.y = 0 (h/silu) or 1 (pe/tanh)
__global__ __launch_bounds__(256, 3) void k_edge2(
    const int* __restrict__ ssend, const int* __restrict__ srec,
    const float* __restrict__ sdist,
    const _Float16* __restrict__ stab, const _Float16* __restrict__ rtab,
    const float* __restrict__ mW1, const float* __restrict__ mb2,
    const float* __restrict__ pW1g, const float* __restrict__ pb2,
    const unsigned short* __restrict__ W2T, const unsigned short* __restrict__ pW2T,
    int layer,
    float* __restrict__ hout, float* __restrict__ pout)
{
    __shared__ __align__(16) float mbuf[4][16][68];
    const int lane = threadIdx.x & 63;
    const int wv = threadIdx.x >> 6;
    const int chunk = (blockIdx.x << 2) + wv;
    if (chunk >= NE / 64) return;
    if (blockIdx.y == 0)
        edge_body<0>(ssend, srec, sdist, stab, rtab,
                     mW1 + (size_t)layer * 16448 + 16384,
                     W2T + layer * 4096, mb2 + layer * 64, hout, chunk, lane, mbuf[wv]);
    else
        edge_body<1>(ssend, srec, sdist, stab + 64, rtab + 64,
                     pW1g + (size_t)layer * 8256 + 8192,
                     pW2T + layer * 4096, pb2 + layer * 64, pout, chunk, lane, mbuf[wv]);
}

// ---------------- final node MLP + pooling (MFMA + segmented flush) ----------------
__global__ __launch_bounds__(256) void k_prepool(
    const float* __restrict__ h, const int* __restrict__ batch,
    const unsigned short* __restrict__ preW1T, const float* __restrict__ b1,
    const unsigned short* __restrict__ preW2T, const float* __restrict__ b2,
    float* __restrict__ pooled)
{
    __shared__ __align__(16) float tl[4][16][68];
    const int lane = threadIdx.x & 63;
    const int wv = threadIdx.x >> 6;
    const int l15 = lane & 15, q = lane >> 4;

    bf16x8 wb1[8], wb2[8];
#pragma unroll
    for (int jt = 0; jt < 4; jt++)
#pragma unroll
        for (int kk = 0; kk < 2; kk++) {
            int off = (jt * 16 + l15) * 64 + kk * 32 + q * 8;
            wb1[jt * 2 + kk] = __builtin_bit_cast(bf16x8, *(const us8*)(preW1T + off));
            wb2[jt * 2 + kk] = __builtin_bit_cast(bf16x8, *(const us8*)(preW2T + off));
        }
    float b1v[4], b2v[4];
#pragma unroll
    for (int jt = 0; jt < 4; jt++) {
        b1v[jt] = b1[jt * 16 + l15];
        b2v[jt] = b2[jt * 16 + l15];
    }

    const int NT = NN / 16;
    for (int tile = blockIdx.x * 4 + wv; tile < NT; tile += gridDim.x * 4) {
        const int rb = tile * 16;
        const int row = rb + l15;
        const int gidl = batch[row];
        const float* hr = h + (size_t)row * 64;
        f32x4 uf[4];
#pragma unroll
        for (int ks = 0; ks < 2; ks++) {
            uf[ks * 2 + 0] = *(const f32x4*)(hr + ks * 32 + q * 8);
            uf[ks * 2 + 1] = *(const f32x4*)(hr + ks * 32 + q * 8 + 4);
        }
        bf16x8 ahi[2], alo[2];
#pragma unroll
        for (int ks = 0; ks < 2; ks++)
#pragma unroll
            for (int i = 0; i < 4; i++) {
                float v0 = uf[ks * 2][i], v1 = uf[ks * 2 + 1][i];
                __bf16 h0 = f2bf(v0), h1 = f2bf(v1);
                ahi[ks][i] = h0; ahi[ks][4 + i] = h1;
                alo[ks][i] = f2bf(v0 - bf2f(h0));
                alo[ks][4 + i] = f2bf(v1 - bf2f(h1));
            }
#pragma unroll
        for (int jt = 0; jt < 4; jt++) {
            f32x4 acc = {0.f, 0.f, 0.f, 0.f};
#pragma unroll
            for (int ks = 0; ks < 2; ks++) {
                acc = __builtin_amdgcn_mfma_f32_16x16x32_bf16(ahi[ks], wb1[jt * 2 + ks], acc, 0, 0, 0);
                acc = __builtin_amdgcn_mfma_f32_16x16x32_bf16(alo[ks], wb1[jt * 2 + ks], acc, 0, 0, 0);
            }
#pragma unroll
            for (int i = 0; i < 4; i++)
                tl[wv][q * 4 + i][jt * 16 + l15] = silu_f(acc[i] + b1v[jt]);
        }
        const float* tr = &tl[wv][l15][0];
        f32x4 u0 = *(const f32x4*)(tr + q * 8);
        f32x4 u1 = *(const f32x4*)(tr + q * 8 + 4);
        f32x4 u2 = *(const f32x4*)(tr + 32 + q * 8);
        f32x4 u3 = *(const f32x4*)(tr + 32 + q * 8 + 4);
        bf16x8 thi[2], tlo[2];
#pragma unroll
        for (int i = 0; i < 4; i++) {
            __bf16 c0 = f2bf(u0[i]), c1 = f2bf(u1[i]), c2 = f2bf(u2[i]), c3 = f2bf(u3[i]);
            thi[0][i] = c0; thi[0][4 + i] = c1; thi[1][i] = c2; thi[1][4 + i] = c3;
            tlo[0][i] = f2bf(u0[i] - bf2f(c0)); tlo[0][4 + i] = f2bf(u1[i] - bf2f(c1));
            tlo[1][i] = f2bf(u2[i] - bf2f(c2)); tlo[1][4 + i] = f2bf(u3[i] - bf2f(c3));
        }
#pragma unroll
        for (int jt = 0; jt < 4; jt++) {
            f32x4 acc = {0.f, 0.f, 0.f, 0.f};
#pragma unroll
            for (int ks = 0; ks < 2; ks++) {
                acc = __builtin_amdgcn_mfma_f32_16x16x32_bf16(thi[ks], wb2[jt * 2 + ks], acc, 0, 0, 0);
                acc = __builtin_amdgcn_mfma_f32_16x16x32_bf16(tlo[ks], wb2[jt * 2 + ks], acc, 0, 0, 0);
            }
#pragma unroll
            for (int i = 0; i < 4; i++)
                tl[wv][q * 4 + i][jt * 16 + l15] = acc[i] + b2v[jt];
        }
        float vh[16];
#pragma unroll
        for (int e = 0; e < 16; e++) vh[e] = tl[wv][e][lane];
        float acc1 = 0.f;
        int cur = -1;
#pragma unroll
        for (int e = 0; e < 16; e++) {
            int ge = __shfl(gidl, e);
            if (ge != cur) {
                if (cur >= 0) atomicAdd(&pooled[(size_t)cur * 64 + lane], acc1);
                cur = ge; acc1 = 0.f;
            }
            acc1 += vh[e];
        }
        if (cur >= 0) atomicAdd(&pooled[(size_t)cur * 64 + lane], acc1);
    }
}

// ---------------- readout ----------------
__global__ __launch_bounds__(256) void k_readout(
    const float* __restrict__ pooled,
    const float* __restrict__ W1, const float* __restrict__ b1,
    const float* __restrict__ W2, const float* __restrict__ b2,
    float* __restrict__ out)
{
    const int lane = threadIdx.x & 63;
    const int wv = threadIdx.x >> 6;
    const int g = (blockIdx.x << 2) + wv;
    if (g >= NG) return;
    const float* pr = pooled + (size_t)g * 64;
    float a0 = 0, a1 = 0, a2 = 0, a3 = 0;
#pragma unroll
    for (int k = 0; k < 64; k += 4) {
        a0 += pr[k] * W1[k * 64 + lane]; a1 += pr[k + 1] * W1[(k + 1) * 64 + lane];
        a2 += pr[k + 2] * W1[(k + 2) * 64 + lane]; a3 += pr[k + 3] * W1[(k + 3) * 64 + lane];
    }
    float v = silu_f(a0 + a1 + a2 + a3 + b1[lane]) * W2[lane];
#pragma unroll
    for (int off = 32; off > 0; off >>= 1) v += __shfl_down(v, off);
    if (lane == 0) out[g] = v + b2[0];
}

extern "C" void kernel_launch(void* const* d_in, const int* in_sizes, int n_in,
                              void* d_out, int out_size, void* d_ws, size_t ws_size,
                              hipStream_t stream)
{
    const float* x = (const float*)d_in[0];
    const float* pos = (const float*)d_in[1];
    const float* pe = (const float*)d_in[2];
    const int* eidx = (const int*)d_in[3];
    const int* batch = (const int*)d_in[4];
    const float* eW = (const float*)d_in[5];
    const float* eb = (const float*)d_in[6];
    const float* epW = (const float*)d_in[7];
    const float* epb = (const float*)d_in[8];
    const float* mW1 = (const float*)d_in[9];
    const float* mb1 = (const float*)d_in[10];
    const float* mW2 = (const float*)d_in[11];
    const float* mb2 = (const float*)d_in[12];
    const float* pW1 = (const float*)d_in[13];
    const float* pb1 = (const float*)d_in[14];
    const float* pW2 = (const float*)d_in[15];
    const float* pb2 = (const float*)d_in[16];
    const float* preW1 = (const float*)d_in[17];
    const float* preb1 = (const float*)d_in[18];
    const float* preW2 = (const float*)d_in[19];
    const float* preb2 = (const float*)d_in[20];
    const float* roW1 = (const float*)d_in[21];
    const float* rob1 = (const float*)d_in[22];
    const float* roW2 = (const float*)d_in[23];
    const float* rob2 = (const float*)d_in[24];

    const int* send = eidx;
    const int* rcv = eidx + NE;

    float* f = (float*)d_ws;
    size_t o = 0;
    float* hA = f + o; o += (size_t)NN * 64;
    float* hB = f + o; o += (size_t)NN * 64;
    float* phA = f + o; o += (size_t)NN * 64;
    float* phB = f + o; o += (size_t)NN * 64;
    _Float16* stab = (_Float16*)(f + o); o += (size_t)NN * 64;
    _Float16* rtab = (_Float16*)(f + o); o += (size_t)NN * 64;
    float* pooled = f + o; o += NG * 64;
    unsigned short* W2T = (unsigned short*)(f + o); o += 8192;
    unsigned short* pW2T = (unsigned short*)(f + o); o += 8192;
    unsigned short* Wswz = (unsigned short*)(f + o); o += 65536;
    unsigned short* WembSwz = (unsigned short*)(f + o); o += 4096;
    unsigned short* preW1T = (unsigned short*)(f + o); o += 2048;
    unsigned short* preW2T = (unsigned short*)(f + o); o += 2048;
    float* biascat = f + o; o += 1024;
    float* biasemb = f + o; o += 128;
    int* hist = (int*)(f + o); o += NN;
    int* cursor = (int*)(f + o); o += NN;
    int* bsum = (int*)(f + o); o += 128;
    int* ssend = (int*)(f + o); o += NE;
    int* srec = (int*)(f + o); o += NE;
    float* sdist = f + o; o += NE;

    hipMemsetAsync(pooled, 0, NG * 64 * sizeof(float), stream);
    hipMemsetAsync(hist, 0, NN * sizeof(int), stream);
    k_wprep<<<512, 256, 0, stream>>>(mW1, mb1, mW2, pW1, pb1, pW2,
                                     eW, eb, epW, epb, preW1, preW2,
                                     W2T, pW2T, Wswz, biascat, WembSwz, biasemb,
                                     preW1T, preW2T);
    k_hist<<<(NE + 255) / 256, 256, 0, stream>>>(rcv, hist);
    k_scan1<<<98, 512, 0, stream>>>(hist, cursor, bsum);
    k_scan2<<<1, 128, 0, stream>>>(bsum);
    k_scatter<<<(NE + 255) / 256, 256, 0, stream>>>(send, rcv, pos, cursor, bsum,
                                                    ssend, srec, sdist);
    k_embed_gemm<<<512, 256, 0, stream>>>(x, pe, WembSwz, biasemb, hA, phA);

    const int EB = (NE / 64 + 3) / 4;
    float* hin = hA; float* pin = phA; float* hout = hB; float* pout = phB;
    for (int l = 0; l < 4; l++) {
        k_node_gemm<<<512, 256, 0, stream>>>(hin, pin, Wswz + (size_t)l * 32768,
                                             biascat + l * 256, stab, rtab, hout, pout);
        k_edge2<<<dim3(EB, 2), 256, 0, stream>>>(ssend, srec, sdist, stab, rtab,
                                                 mW1, mb2, pW1, pb2, W2T, pW2T, l,
                                                 hout, pout);
        float* t;
        t = hin; hin = hout; hout = t;
        t = pin; pin = pout; pout = t;
    }
    k_prepool<<<512, 256, 0, stream>>>(hin, batch, preW1T, preb1, preW2T, preb2, pooled);
    k_readout<<<128, 256, 0, stream>>>(pooled, roW1, rob1, roW2, rob2, (float*)d_out);
}